// Round 8
// baseline (479.485 us; speedup 1.0000x reference)
//
#include <hip/hip_runtime.h>
#include <hip/hip_cooperative_groups.h>
#include <math.h>

namespace cg = cooperative_groups;

#define WDIM 4096
#define SDIM 4096
#define NKEYS 1024
#define SHARP 10.0f
#define NBLK 256
#define BSZ 1024

typedef float v4 __attribute__((ext_vector_type(4)));

__device__ __forceinline__ float wave_reduce_sum(float v) {
#pragma unroll
    for (int off = 32; off > 0; off >>= 1) v += __shfl_down(v, off, 64);
    return v;
}

// Whole pipeline in ONE cooperative kernel: 256 blocks x 1024 threads
// (1 block/CU co-resident, 16 waves/CU = the occupancy k_mix measured best
// at). Four 256-thread groups per block run the measured-best per-phase
// bodies; grid.sync() replaces 4 kernel boundaries + the memset dispatch
// (~30 us of graph-serialized launch overhead in r7's accounting).
// All holo/cue traffic NT (r7 A/B: NT streams beat L3-hit reads).
__global__ __launch_bounds__(BSZ) void k_fused(
    const float* __restrict__ hr, const float* __restrict__ hi,
    const float* __restrict__ cr, const float* __restrict__ ci,
    const float* __restrict__ kr, const float* __restrict__ ki,
    float* __restrict__ mix_re, float* __restrict__ mix_im,
    float* __restrict__ corr,
    float* __restrict__ cre, float* __restrict__ cim,
    float* __restrict__ out_re, float* __restrict__ out_im) {
    cg::grid_group grid = cg::this_grid();
    const int b = blockIdx.x;
    const int t = threadIdx.x;
    const int g = t >> 8;          // 256-thread group 0..3
    const int tt = t & 255;        // thread-in-group
    const int wv = (t >> 6) & 3;   // wave-in-group
    const int lane = t & 63;

    __shared__ float rr[4][4], ri[4][4];
    __shared__ float red[4][256];

    // ---- P0: zero clean accumulators (cre/cim contiguous = 8192 floats);
    // consumed in P3, two grid.syncs later.
    {
        const int gid = b * BSZ + t;
        if (gid < 2 * WDIM) cre[gid] = 0.f;
    }

    // ---- P1: mix[w] = sum_s holo[w,s]*conj(cue[w,s]); 16 rows/block ----
    // re = hr*cr + hi*ci ; im = hi*cr - hr*ci
#pragma unroll 1
    for (int r = 0; r < 4; ++r) {
        const int w = b * 16 + r * 4 + g;
        const size_t base = (size_t)w * SDIM;
        const v4* hr4 = (const v4*)(hr + base);
        const v4* hi4 = (const v4*)(hi + base);
        const v4* cr4 = (const v4*)(cr + base);
        const v4* ci4 = (const v4*)(ci + base);
        v4 A[4], B[4], C[4], D[4];
#pragma unroll
        for (int j = 0; j < 4; ++j) {
            const int idx = tt + j * 256;
            C[j] = __builtin_nontemporal_load(cr4 + idx);
            D[j] = __builtin_nontemporal_load(ci4 + idx);
        }
#pragma unroll
        for (int j = 0; j < 4; ++j) {
            const int idx = tt + j * 256;
            A[j] = __builtin_nontemporal_load(hr4 + idx);
            B[j] = __builtin_nontemporal_load(hi4 + idx);
        }
        float sr = 0.f, si = 0.f;
#pragma unroll
        for (int j = 0; j < 4; ++j) {
            sr += A[j].x * C[j].x + B[j].x * D[j].x;  si += B[j].x * C[j].x - A[j].x * D[j].x;
            sr += A[j].y * C[j].y + B[j].y * D[j].y;  si += B[j].y * C[j].y - A[j].y * D[j].y;
            sr += A[j].z * C[j].z + B[j].z * D[j].z;  si += B[j].z * C[j].z - A[j].z * D[j].z;
            sr += A[j].w * C[j].w + B[j].w * D[j].w;  si += B[j].w * C[j].w - A[j].w * D[j].w;
        }
        sr = wave_reduce_sum(sr);
        si = wave_reduce_sum(si);
        if (lane == 0) { rr[g][wv] = sr; ri[g][wv] = si; }
        __syncthreads();
        if (tt == 0) {
            mix_re[w] = rr[g][0] + rr[g][1] + rr[g][2] + rr[g][3];
            mix_im[w] = ri[g][0] + ri[g][1] + ri[g][2] + ri[g][3];
        }
        __syncthreads();
    }

    grid.sync();

    // ---- P2: corr[n] = |keys[n,:] . mix| * SHARP (plain dot); 4 keys/block
    // zr = kr*mr - ki*mi ; zi = kr*mi + ki*mr
    {
        const int n = b * 4 + g;
        const size_t base = (size_t)n * WDIM;
        const v4* kr4 = (const v4*)(kr + base);
        const v4* ki4 = (const v4*)(ki + base);
        const v4* mr4 = (const v4*)mix_re;
        const v4* mi4 = (const v4*)mix_im;
        v4 A[4], B[4], M[4], Q[4];
#pragma unroll
        for (int j = 0; j < 4; ++j) {
            const int idx = tt + j * 256;
            A[j] = kr4[idx];
            B[j] = ki4[idx];
            M[j] = mr4[idx];
            Q[j] = mi4[idx];
        }
        float zr = 0.f, zi = 0.f;
#pragma unroll
        for (int j = 0; j < 4; ++j) {
            zr += A[j].x * M[j].x - B[j].x * Q[j].x;  zi += A[j].x * Q[j].x + B[j].x * M[j].x;
            zr += A[j].y * M[j].y - B[j].y * Q[j].y;  zi += A[j].y * Q[j].y + B[j].y * M[j].y;
            zr += A[j].z * M[j].z - B[j].z * Q[j].z;  zi += A[j].z * Q[j].z + B[j].z * M[j].z;
            zr += A[j].w * M[j].w - B[j].w * Q[j].w;  zi += A[j].w * Q[j].w + B[j].w * M[j].w;
        }
        zr = wave_reduce_sum(zr);
        zi = wave_reduce_sum(zi);
        if (lane == 0) { rr[g][wv] = zr; ri[g][wv] = zi; }
        __syncthreads();
        if (tt == 0) {
            const float fr = rr[g][0] + rr[g][1] + rr[g][2] + rr[g][3];
            const float fi = ri[g][0] + ri[g][1] + ri[g][2] + ri[g][3];
            corr[n] = sqrtf(fr * fr + fi * fi) * SHARP;
        }
    }

    grid.sync();

    // ---- P3: softmax (recomputed per group, 4 KB L2 reads) + clean partial
    // 1024 tasks: task G owns w-tile wt=G>>8 and 4 keys n0=(G&255)*4;
    // atomicAdd into zeroed cre/cim.
    {
        const float v0 = corr[tt], v1 = corr[tt + 256],
                    v2 = corr[tt + 512], v3 = corr[tt + 768];
        float mloc = fmaxf(fmaxf(v0, v1), fmaxf(v2, v3));
        red[g][tt] = mloc; __syncthreads();
        for (int s = 128; s > 0; s >>= 1) {
            if (tt < s) red[g][tt] = fmaxf(red[g][tt], red[g][tt + s]);
            __syncthreads();
        }
        const float mx = red[g][0];
        __syncthreads();
        float sum = expf(v0 - mx) + expf(v1 - mx) + expf(v2 - mx) + expf(v3 - mx);
        red[g][tt] = sum; __syncthreads();
        for (int s = 128; s > 0; s >>= 1) {
            if (tt < s) red[g][tt] += red[g][tt + s];
            __syncthreads();
        }
        const float inv = 1.0f / red[g][0];

        const int G = b * 4 + g;     // 0..1023
        const int wt = G >> 8;       // 0..3
        const int n0 = (G & 255) * 4;
        const int f4 = wt * 256 + tt;
        float arx = 0.f, ary = 0.f, arz = 0.f, arw = 0.f;
        float aix = 0.f, aiy = 0.f, aiz = 0.f, aiw = 0.f;
#pragma unroll
        for (int j = 0; j < 4; ++j) {
            const int n = n0 + j;
            const float a = expf(corr[n] - mx) * inv;
            const v4 x = ((const v4*)(kr + (size_t)n * WDIM))[f4];
            const v4 y = ((const v4*)(ki + (size_t)n * WDIM))[f4];
            arx += a * x.x; ary += a * x.y; arz += a * x.z; arw += a * x.w;
            aix += a * y.x; aiy += a * y.y; aiz += a * y.z; aiw += a * y.w;
        }
        const int w = f4 * 4;
        atomicAdd(&cre[w + 0], arx); atomicAdd(&cre[w + 1], ary);
        atomicAdd(&cre[w + 2], arz); atomicAdd(&cre[w + 3], arw);
        atomicAdd(&cim[w + 0], aix); atomicAdd(&cim[w + 1], aiy);
        atomicAdd(&cim[w + 2], aiz); atomicAdd(&cim[w + 3], aiw);
    }

    grid.sync();

    // ---- P4: out = holo * clean[w]; 16 rows/block, NT loads + NT stores
    // out_re = hr*a - hi*b ; out_im = hr*b + hi*a
#pragma unroll 1
    for (int r = 0; r < 4; ++r) {
        const int w = b * 16 + r * 4 + g;
        const size_t base = (size_t)w * SDIM;
        const float a = cre[w], bc = cim[w];
        const v4* hr4 = (const v4*)(hr + base);
        const v4* hi4 = (const v4*)(hi + base);
        v4* or4 = (v4*)(out_re + base);
        v4* oi4 = (v4*)(out_im + base);
        v4 H[4], G4[4];
#pragma unroll
        for (int j = 0; j < 4; ++j) {
            const int i = tt + j * 256;
            H[j] = __builtin_nontemporal_load(hr4 + i);
            G4[j] = __builtin_nontemporal_load(hi4 + i);
        }
#pragma unroll
        for (int j = 0; j < 4; ++j) {
            const int i = tt + j * 256;
            v4 orr, oii;
            orr.x = H[j].x * a - G4[j].x * bc;  oii.x = H[j].x * bc + G4[j].x * a;
            orr.y = H[j].y * a - G4[j].y * bc;  oii.y = H[j].y * bc + G4[j].y * a;
            orr.z = H[j].z * a - G4[j].z * bc;  oii.z = H[j].z * bc + G4[j].z * a;
            orr.w = H[j].w * a - G4[j].w * bc;  oii.w = H[j].w * bc + G4[j].w * a;
            __builtin_nontemporal_store(orr, or4 + i);
            __builtin_nontemporal_store(oii, oi4 + i);
        }
    }
}

extern "C" void kernel_launch(void* const* d_in, const int* in_sizes, int n_in,
                              void* d_out, int out_size, void* d_ws, size_t ws_size,
                              hipStream_t stream) {
    const float* hr = (const float*)d_in[0];
    const float* hi = (const float*)d_in[1];
    const float* cr = (const float*)d_in[2];
    const float* ci = (const float*)d_in[3];
    const float* kr = (const float*)d_in[4];
    const float* ki = (const float*)d_in[5];

    float* ws = (float*)d_ws;
    float* mix_re = ws;                 // 4096
    float* mix_im = ws + 4096;          // 4096
    float* corr   = ws + 8192;          // 1024
    float* cre    = ws + 10240;         // 4096
    float* cim    = ws + 14336;         // 4096 (contiguous with cre)

    float* out_re = (float*)d_out;
    float* out_im = out_re + (size_t)WDIM * SDIM;

    void* args[] = {
        (void*)&hr, (void*)&hi, (void*)&cr, (void*)&ci,
        (void*)&kr, (void*)&ki,
        (void*)&mix_re, (void*)&mix_im, (void*)&corr,
        (void*)&cre, (void*)&cim,
        (void*)&out_re, (void*)&out_im,
    };
    hipLaunchCooperativeKernel((void*)k_fused, dim3(NBLK), dim3(BSZ),
                               args, 0, stream);
}

// Round 9
// 358.231 us; speedup vs baseline: 1.3385x; 1.3385x over previous
//
#include <hip/hip_runtime.h>
#include <math.h>

#define WDIM 4096
#define SDIM 4096
#define NKEYS 1024
#define SHARP 10.0f

typedef float v4 __attribute__((ext_vector_type(4)));

__device__ __forceinline__ float wave_reduce_sum(float v) {
#pragma unroll
    for (int off = 32; off > 0; off >>= 1) v += __shfl_down(v, off, 64);
    return v;
}

// SESSION-BEST CONFIG (r7, 358.8 us) restored after the cooperative-fusion
// experiment (r8) regressed to 479 us: single-dispatch fusion forced all
// reads into L3-hit streams (~2.6 TB/s wall) and added grid.sync overhead.
// Key finding across rounds: NT HBM streams (~3.5 TB/s/kernel) beat L3-hit
// reads (~1.75 TB/s); keep holo+cue NT everywhere, keys plain (reused).

// K1: noisy_mix[w] = sum_s holo[w,s] * conj(cue[w,s])
// One row per 256-thread block; all loads NT (holo never allocates in L3,
// both k_mix and k_out read it as an HBM stream).
// re = hr*cr + hi*ci ; im = hi*cr - hr*ci
__global__ __launch_bounds__(256) void k_mix(
    const float* __restrict__ hr, const float* __restrict__ hi,
    const float* __restrict__ cr, const float* __restrict__ ci,
    float* __restrict__ mix_re, float* __restrict__ mix_im) {
    const int w = blockIdx.x;
    const int t = threadIdx.x;
    const int wave = t >> 6, lane = t & 63;
    const size_t base = (size_t)w * SDIM;
    const v4* hr4 = (const v4*)(hr + base);
    const v4* hi4 = (const v4*)(hi + base);
    const v4* cr4 = (const v4*)(cr + base);
    const v4* ci4 = (const v4*)(ci + base);
    v4 a[4], b[4], c[4], d[4];
#pragma unroll
    for (int j = 0; j < 4; ++j) {
        const int idx = t + j * 256;
        c[j] = __builtin_nontemporal_load(cr4 + idx);
        d[j] = __builtin_nontemporal_load(ci4 + idx);
    }
#pragma unroll
    for (int j = 0; j < 4; ++j) {
        const int idx = t + j * 256;
        a[j] = __builtin_nontemporal_load(hr4 + idx);
        b[j] = __builtin_nontemporal_load(hi4 + idx);
    }
    float sr = 0.f, si = 0.f;
#pragma unroll
    for (int j = 0; j < 4; ++j) {
        sr += a[j].x * c[j].x + b[j].x * d[j].x;  si += b[j].x * c[j].x - a[j].x * d[j].x;
        sr += a[j].y * c[j].y + b[j].y * d[j].y;  si += b[j].y * c[j].y - a[j].y * d[j].y;
        sr += a[j].z * c[j].z + b[j].z * d[j].z;  si += b[j].z * c[j].z - a[j].z * d[j].z;
        sr += a[j].w * c[j].w + b[j].w * d[j].w;  si += b[j].w * c[j].w - a[j].w * d[j].w;
    }
    sr = wave_reduce_sum(sr);
    si = wave_reduce_sum(si);
    __shared__ float rr[4], ri[4];
    if (lane == 0) { rr[wave] = sr; ri[wave] = si; }
    __syncthreads();
    if (t == 0) {
        mix_re[w] = rr[0] + rr[1] + rr[2] + rr[3];
        mix_im[w] = ri[0] + ri[1] + ri[2] + ri[3];
    }
}

// K2: corr[n] = |sum_w keys[n,w] * mix[w]| * SHARP (plain dot, NO conjugation)
// One key per 256-thread block. Keys loaded PLAIN on purpose: small (32 MiB),
// re-read by k_clean and across iterations -> want L3 allocation.
__global__ __launch_bounds__(256) void k_corr(
    const float* __restrict__ kr, const float* __restrict__ ki,
    const float* __restrict__ mr, const float* __restrict__ mi,
    float* __restrict__ corr) {
    const int n = blockIdx.x;
    const int t = threadIdx.x;
    const int wave = t >> 6, lane = t & 63;
    const size_t base = (size_t)n * WDIM;
    const v4* kr4 = (const v4*)(kr + base);
    const v4* ki4 = (const v4*)(ki + base);
    const v4* mr4 = (const v4*)mr;
    const v4* mi4 = (const v4*)mi;
    v4 a[4], b[4], m[4], q[4];
#pragma unroll
    for (int j = 0; j < 4; ++j) {
        const int idx = t + j * 256;
        a[j] = kr4[idx];
        b[j] = ki4[idx];
        m[j] = mr4[idx];
        q[j] = mi4[idx];
    }
    float zr = 0.f, zi = 0.f;
#pragma unroll
    for (int j = 0; j < 4; ++j) {
        zr += a[j].x * m[j].x - b[j].x * q[j].x;  zi += a[j].x * q[j].x + b[j].x * m[j].x;
        zr += a[j].y * m[j].y - b[j].y * q[j].y;  zi += a[j].y * q[j].y + b[j].y * m[j].y;
        zr += a[j].z * m[j].z - b[j].z * q[j].z;  zi += a[j].z * q[j].z + b[j].z * m[j].z;
        zr += a[j].w * m[j].w - b[j].w * q[j].w;  zi += a[j].w * q[j].w + b[j].w * m[j].w;
    }
    zr = wave_reduce_sum(zr);
    zi = wave_reduce_sum(zi);
    __shared__ float rr[4], ri[4];
    if (lane == 0) { rr[wave] = zr; ri[wave] = zi; }
    __syncthreads();
    if (t == 0) {
        const float fr = rr[0] + rr[1] + rr[2] + rr[3];
        const float fi = ri[0] + ri[1] + ri[2] + ri[3];
        corr[n] = sqrtf(fr * fr + fi * fi) * SHARP;
    }
}

// K3+K4 fused: each block recomputes the 1024-wide softmax from corr
// (4 KB L2-hit read, fully parallel), then does its 16-key partial of
// clean_key[w] = sum_n att[n]*keys[n,w], atomicAdd into zeroed cre/cim.
__global__ __launch_bounds__(256) void k_clean(
    const float* __restrict__ kr, const float* __restrict__ ki,
    const float* __restrict__ corr,
    float* __restrict__ clean_re, float* __restrict__ clean_im) {
    const int t = threadIdx.x;
    __shared__ float red[256];
    __shared__ float satt[16];

    // --- softmax over the 1024 logits (redundant per block, cheap) ---
    float v0 = corr[t], v1 = corr[t + 256], v2 = corr[t + 512], v3 = corr[t + 768];
    float m = fmaxf(fmaxf(v0, v1), fmaxf(v2, v3));
    red[t] = m; __syncthreads();
    for (int s = 128; s > 0; s >>= 1) {
        if (t < s) red[t] = fmaxf(red[t], red[t + s]);
        __syncthreads();
    }
    const float mx = red[0];
    __syncthreads();
    float sum = expf(v0 - mx) + expf(v1 - mx) + expf(v2 - mx) + expf(v3 - mx);
    red[t] = sum; __syncthreads();
    for (int s = 128; s > 0; s >>= 1) {
        if (t < s) red[t] += red[t + s];
        __syncthreads();
    }
    const float inv = 1.0f / red[0];
    const int n0 = blockIdx.y * 16;
    if (t < 16) satt[t] = expf(corr[n0 + t] - mx) * inv;
    __syncthreads();

    // --- 16-key partial column sums ---
    const int wt = blockIdx.x;            // 0..3
    const int f4 = wt * 256 + t;
    float arx = 0.f, ary = 0.f, arz = 0.f, arw = 0.f;
    float aix = 0.f, aiy = 0.f, aiz = 0.f, aiw = 0.f;
#pragma unroll 1
    for (int jt = 0; jt < 4; ++jt) {
        v4 x[4], y[4]; float a[4];
#pragma unroll
        for (int j = 0; j < 4; ++j) {
            const int n = n0 + jt * 4 + j;
            a[j] = satt[jt * 4 + j];
            x[j] = ((const v4*)(kr + (size_t)n * WDIM))[f4];
            y[j] = ((const v4*)(ki + (size_t)n * WDIM))[f4];
        }
#pragma unroll
        for (int j = 0; j < 4; ++j) {
            arx += a[j] * x[j].x; ary += a[j] * x[j].y; arz += a[j] * x[j].z; arw += a[j] * x[j].w;
            aix += a[j] * y[j].x; aiy += a[j] * y[j].y; aiz += a[j] * y[j].z; aiw += a[j] * y[j].w;
        }
    }
    const int w = f4 * 4;
    atomicAdd(&clean_re[w + 0], arx); atomicAdd(&clean_re[w + 1], ary);
    atomicAdd(&clean_re[w + 2], arz); atomicAdd(&clean_re[w + 3], arw);
    atomicAdd(&clean_im[w + 0], aix); atomicAdd(&clean_im[w + 1], aiy);
    atomicAdd(&clean_im[w + 2], aiz); atomicAdd(&clean_im[w + 3], aiw);
}

// K5: out = holo * clean_key[w] — one block/row, NT holo loads (holo stays
// HBM-resident since k_mix also reads it NT), NT stores.
// out_re = hr*a - hi*b ; out_im = hr*b + hi*a
__global__ __launch_bounds__(256) void k_out(
    const float* __restrict__ hr, const float* __restrict__ hi,
    const float* __restrict__ cre, const float* __restrict__ cim,
    float* __restrict__ out_re, float* __restrict__ out_im) {
    const int w = blockIdx.x;
    const size_t base = (size_t)w * SDIM;
    const float a = cre[w], b = cim[w];
    const v4* hr4 = (const v4*)(hr + base);
    const v4* hi4 = (const v4*)(hi + base);
    v4* or4 = (v4*)(out_re + base);
    v4* oi4 = (v4*)(out_im + base);
    v4 h[4], g[4];
#pragma unroll
    for (int j = 0; j < 4; ++j) {
        const int i = threadIdx.x + j * 256;
        h[j] = __builtin_nontemporal_load(hr4 + i);
        g[j] = __builtin_nontemporal_load(hi4 + i);
    }
#pragma unroll
    for (int j = 0; j < 4; ++j) {
        const int i = threadIdx.x + j * 256;
        v4 orr, oii;
        orr.x = h[j].x * a - g[j].x * b;  oii.x = h[j].x * b + g[j].x * a;
        orr.y = h[j].y * a - g[j].y * b;  oii.y = h[j].y * b + g[j].y * a;
        orr.z = h[j].z * a - g[j].z * b;  oii.z = h[j].z * b + g[j].z * a;
        orr.w = h[j].w * a - g[j].w * b;  oii.w = h[j].w * b + g[j].w * a;
        __builtin_nontemporal_store(orr, or4 + i);
        __builtin_nontemporal_store(oii, oi4 + i);
    }
}

extern "C" void kernel_launch(void* const* d_in, const int* in_sizes, int n_in,
                              void* d_out, int out_size, void* d_ws, size_t ws_size,
                              hipStream_t stream) {
    const float* hr = (const float*)d_in[0];
    const float* hi = (const float*)d_in[1];
    const float* cr = (const float*)d_in[2];
    const float* ci = (const float*)d_in[3];
    const float* kr = (const float*)d_in[4];
    const float* ki = (const float*)d_in[5];

    float* ws = (float*)d_ws;
    float* mix_re = ws;                 // 4096
    float* mix_im = ws + 4096;          // 4096
    float* corr   = ws + 8192;          // 1024
    float* cre    = ws + 10240;         // 4096
    float* cim    = ws + 14336;         // 4096 (contiguous with cre)

    float* out_re = (float*)d_out;
    float* out_im = out_re + (size_t)WDIM * SDIM;

    // memset first: off the dependency chain until k_clean needs it
    hipMemsetAsync(cre, 0, 2 * WDIM * sizeof(float), stream);
    k_mix<<<WDIM, 256, 0, stream>>>(hr, hi, cr, ci, mix_re, mix_im);
    k_corr<<<NKEYS, 256, 0, stream>>>(kr, ki, mix_re, mix_im, corr);
    k_clean<<<dim3(4, 64), 256, 0, stream>>>(kr, ki, corr, cre, cim);
    k_out<<<WDIM, 256, 0, stream>>>(hr, hi, cre, cim, out_re, out_im);
}